// Round 1
// 1275.243 us; speedup vs baseline: 1.1226x; 1.1226x over previous
//
#include <hip/hip_runtime.h>
#include <hip/hip_bf16.h>

#define NLAY 8
#define MFMA __builtin_amdgcn_mfma_f32_16x16x32_bf16
#define MFMA32 __builtin_amdgcn_mfma_f32_32x32x16_bf16

typedef __attribute__((ext_vector_type(8))) short bf16x8;
typedef __attribute__((ext_vector_type(4))) float f32x4;
typedef __attribute__((ext_vector_type(16))) float f32x16;
typedef __attribute__((ext_vector_type(4))) int i32x4;

template <bool BF16>
__device__ __forceinline__ float ld(const void* p, int i) {
  if (BF16) {
    unsigned short u = ((const unsigned short*)p)[i];
    return __uint_as_float(((unsigned)u) << 16);
  }
  return ((const float*)p)[i];
}

template <bool BF16>
__device__ __forceinline__ float2 ld2(const void* p, int i) {  // i even
  float2 r;
  if (BF16) {
    unsigned u = ((const unsigned*)p)[i >> 1];
    r.x = __uint_as_float(u << 16);
    r.y = __uint_as_float(u & 0xffff0000u);
  } else {
    r = ((const float2*)p)[i >> 1];
  }
  return r;
}

__device__ __forceinline__ float bfu(unsigned short u) {
  return __uint_as_float(((unsigned)u) << 16);
}

__device__ __forceinline__ unsigned pack_bf2(float a, float b) {
  __hip_bfloat16 ha = __float2bfloat16(a), hb = __float2bfloat16(b);
  unsigned short ua, ub;
  __builtin_memcpy(&ua, &ha, 2);
  __builtin_memcpy(&ub, &hb, 2);
  return ((unsigned)ub << 16) | (unsigned)ua;
}

__device__ __forceinline__ float2 unpk(unsigned u) {
  float2 r;
  r.x = __uint_as_float(u << 16);
  r.y = __uint_as_float(u & 0xffff0000u);
  return r;
}

__device__ __forceinline__ bf16x8 as_bf(i32x4 v) {
  bf16x8 r;
  __builtin_memcpy(&r, &v, 16);
  return r;
}

// ws[0..271]=sin, ws[272..543]=cos, ws[544..1699]=dmask, ws[1700]=dtype flag
__global__ void setup_tables(float* __restrict__ ws, const void* __restrict__ x) {
  int tid = threadIdx.x;
  for (int idx = tid; idx < 272; idx += 256) {
    int t = idx >> 4, j = idx & 15;
    float a = powf(10000.f, -(float)(j >> 1) / 7.f);
    float arg = (float)t * a;
    ws[idx] = sinf(arg);
    ws[272 + idx] = cosf(arg);
  }
  for (int row = tid; row < 68; row += 256) {
    int hh = row / 17, t = row % 17;
    float gamma = 1.f - exp2f(-5.f - 4.f * (float)hh / 3.f);
    float sum = 0.f;
    for (int u = 0; u <= t; ++u) sum += powf(gamma, (float)(t - u));
    float rn = rsqrtf(sum);
    for (int u = 0; u < 17; ++u)
      ws[544 + row * 17 + u] = (u <= t) ? powf(gamma, (float)(t - u)) * rn : 0.f;
  }
  if (tid == 0) {
    const unsigned short* u16 = (const unsigned short*)x;
    int sane = 0;
    for (int i = 0; i < 128; ++i) {
      float v = __uint_as_float(((unsigned)u16[2 * i]) << 16);
      float av = fabsf(v);
      if (v == 0.f || (av > 1e-8f && av < 1e4f)) sane++;
    }
    ws[1700] = (sane >= 64) ? 1.f : 0.f;
  }
}

// Pre-swizzle weights into MFMA B-fragment order (bf16), into ws+8192 bytes.
#define FRAG_TOT 280576
template <bool BF16>
__global__ void prep_frags(const void* __restrict__ patch_w,
                           const void* __restrict__ Wq, const void* __restrict__ Wk,
                           const void* __restrict__ Wv, const void* __restrict__ Wg,
                           const void* __restrict__ Wo, const void* __restrict__ w1,
                           const float* __restrict__ tab,
                           unsigned short* __restrict__ frag) {
  if ((tab[1700] > 0.5f) != BF16) return;
  int g = blockIdx.x * 256 + threadIdx.x;
  if (g >= FRAG_TOT) return;
  float v;
  if (g < 12288) {  // patch_w: K=192 (kt6), N=64 (nt4)
    int nt = g / 3072, r = g % 3072, kt = r / 512, r2 = r % 512, la = r2 >> 3, j = r2 & 7;
    int n = nt * 16 + (la & 15), k = kt * 32 + (la >> 4) * 8 + j;
    v = ld<BF16>(patch_w, k * 64 + n);
  } else {
    int gg = g - 12288, l = gg / 33536, o = gg % 33536;
    if (o < 8192) {  // Wq / Wk
      const void* W = (o < 4096) ? Wq : Wk;
      int e = o & 4095;
      int nt = e / 1024, r = e % 1024, kt = r / 512, r2 = r % 512, la = r2 >> 3, j = r2 & 7;
      int n = nt * 16 + (la & 15), k = kt * 32 + (la >> 4) * 8 + j;
      v = ld<BF16>(W, l * 4096 + k * 64 + n);
    } else if (o < 24576) {  // Wv / Wg
      const void* W = (o < 16384) ? Wv : Wg;
      int e = (o - 8192) & 8191;
      int nt = e / 1024, r = e % 1024, kt = r / 512, r2 = r % 512, la = r2 >> 3, j = r2 & 7;
      int n = nt * 16 + (la & 15), k = kt * 32 + (la >> 4) * 8 + j;
      v = ld<BF16>(W, l * 8192 + k * 128 + n);
    } else if (o < 32768) {  // Wo
      int e = o - 24576;
      int nt = e / 2048, r = e % 2048, kt = r / 512, r2 = r % 512, la = r2 >> 3, j = r2 & 7;
      int n = nt * 16 + (la & 15), k = kt * 32 + (la >> 4) * 8 + j;
      v = ld<BF16>(Wo, l * 8192 + k * 64 + n);
    } else {  // w1T[e][d] = w1[d][e]
      int e = o - 32768, eo = e / 64, d = e % 64;
      v = ld<BF16>(w1, l * 768 + d * 12 + eo);
    }
  }
  __hip_bfloat16 h = __float2bfloat16(v);
  unsigned short us;
  __builtin_memcpy(&us, &h, 2);
  frag[g] = us;
}

// LDS float offsets
#define O_DM   0      // 1156
#define O_SIN  1156   // 272
#define O_COS  1428   // 272
#define O_ST   1700   // 512
#define O_H    2212   // 2244: H fp32 34x66
#define O_XNF  4456   // 1536: XN A-frags / XNp bf16 34x72
#define O_FF   5992   // 408
#define O_R    6400   // 4616: Q 34x68 + KT 2x64x18 / alias O fp32 34x130
#define O_SCA  11016  // 3072: patch A-frags / SC fp32 2x4x17x20 (2720) / OA frags
#define O_VG   14088  // 4872: VT bf16 2x128x20 (2560 f) + G bf16 34x136 (2312 f)
#define SM_TOT 18960

template <bool BF16>
__global__ void __launch_bounds__(512)
vit_fused(const void* __restrict__ x, const void* __restrict__ patch_b,
          const void* __restrict__ cls, const void* __restrict__ pos,
          const void* __restrict__ ln1s, const void* __restrict__ ln1b,
          const void* __restrict__ b1, const void* __restrict__ w2,
          const void* __restrict__ b2, const void* __restrict__ ln2s,
          const void* __restrict__ ln2b, const void* __restrict__ lnfs,
          const void* __restrict__ lnfb, const void* __restrict__ neckw,
          const void* __restrict__ neckb, const void* __restrict__ headw,
          const void* __restrict__ headb, const float* __restrict__ tab,
          const unsigned short* __restrict__ FR, void* __restrict__ out) {
  if ((tab[1700] > 0.5f) != BF16) return;

  const int tid = threadIdx.x;
  const int lane = tid & 63, w = tid >> 6;  // w in 0..7
  const int lq = lane >> 4, ln = lane & 15;
  const int img0 = 2 * blockIdx.x;

  __shared__ __align__(16) float sm[SM_TOT];
  float* sDM  = sm + O_DM;
  float* sSin = sm + O_SIN;
  float* sCos = sm + O_COS;
  float* sST  = sm + O_ST;
  float* sH   = sm + O_H;
  float* sFF  = sm + O_FF;
  float* sQ   = sm + O_R;          // 34x68
  float* sKT  = sm + O_R + 2312;   // 2 x 64x18
  float* sO   = sm + O_R;          // alias, 34x130
  float* sSC  = sm + O_SCA;        // 2 x 4 x 17 x 20 (pitch-20 rows)
  unsigned short* sVbT = (unsigned short*)(sm + O_VG);          // 2 x 128 x 20 (c-major, u inner)
  unsigned short* sGb  = (unsigned short*)(sm + O_VG) + 5120;   // 34x136
  const bf16x8* FRB = (const bf16x8*)FR;

  // ---- stage tables + patch A-frags + cls rows ----
  for (int i = tid; i < 1156; i += 512) sDM[i] = tab[544 + i];
  for (int i = tid; i < 272; i += 512) { sSin[i] = tab[i]; sCos[i] = tab[272 + i]; }
  for (int s = tid; s < 768; s += 512) {  // patch A-frags into O_SCA
    int mt = s / 384, r = s % 384, kt = r / 64, la = r % 64;
    int p = la & 15, q = la >> 4;
    int kb = kt * 32 + q * 8;
    int c = kb >> 6, rem = kb & 63, a = rem >> 3;
    int pi = p >> 2, pj = p & 3;
    int src = (img0 + mt) * 3072 + c * 1024 + (pi * 8 + a) * 32 + pj * 8;
    float v[8];
#pragma unroll
    for (int t2 = 0; t2 < 8; t2 += 2) {
      float2 pv = ld2<BF16>(x, src + t2);
      v[t2] = pv.x; v[t2 + 1] = pv.y;
    }
    i32x4 pk;
    pk.x = pack_bf2(v[0], v[1]); pk.y = pack_bf2(v[2], v[3]);
    pk.z = pack_bf2(v[4], v[5]); pk.w = pack_bf2(v[6], v[7]);
    ((i32x4*)(sm + O_SCA))[s] = pk;
  }
  if (tid < 128) {  // cls token rows
    int img = tid >> 6, n = tid & 63;
    sH[(img * 17) * 66 + n] = ld<BF16>(cls, n) + ld<BF16>(pos, n);
  }
  __syncthreads();

  // ---- patch embed MFMA: 8 jobs = 2mt x 4nt, one per wave ----
  {
    int mt = w >> 2, nt = w & 3;
    f32x4 acc = {0.f, 0.f, 0.f, 0.f};
    const bf16x8* paf = (const bf16x8*)(sm + O_SCA);
#pragma unroll
    for (int kt = 0; kt < 6; ++kt)
      acc = MFMA(paf[(mt * 6 + kt) * 64 + lane], FRB[(nt * 6 + kt) * 64 + lane], acc, 0, 0, 0);
    int n = nt * 16 + ln;
    float pb = ld<BF16>(patch_b, n);
#pragma unroll
    for (int i = 0; i < 4; ++i) {
      int t = 1 + lq * 4 + i;
      sH[(mt * 17 + t) * 66 + n] = acc[i] + pb + ld<BF16>(pos, t * 64 + n);
    }
  }
  __syncthreads();

  for (int l = 0; l < NLAY; ++l) {
    const int LB = 1536 + l * 4192;  // layer base, bf16x8 slots

    // ---- ln1 stats: 8 lanes per row + shuffle reduce ----
    if (tid < 272) {
      int m = tid >> 3, sub = tid & 7;
      const float* hp = sH + m * 66 + sub * 8;
      float s1 = 0.f, s2 = 0.f;
#pragma unroll
      for (int i = 0; i < 8; ++i) { float v = hp[i]; s1 += v; s2 += v * v; }
      s1 += __shfl_xor(s1, 1); s2 += __shfl_xor(s2, 1);
      s1 += __shfl_xor(s1, 2); s2 += __shfl_xor(s2, 2);
      s1 += __shfl_xor(s1, 4); s2 += __shfl_xor(s2, 4);
      if (sub == 0) {
        float mu = s1 * (1.f / 64.f);
        float var = s2 * (1.f / 64.f) - mu * mu;
        sST[m] = mu;
        sST[34 + m] = rsqrtf(var + 1e-5f);
      }
    }
    __syncthreads();

    // ---- ln1 -> XN A-frags (bf16) ----
    for (int s = tid; s < 384; s += 512) {
      int mt = s >> 7, kt = (s >> 6) & 1, la = s & 63;
      int m = mt * 16 + (la & 15), q = la >> 4;
      int kb = kt * 32 + q * 8;
      i32x4 pk = {0, 0, 0, 0};
      if (m < 34) {
        float mu = sST[m], rr = sST[34 + m];
        float vv[8];
#pragma unroll
        for (int t2 = 0; t2 < 8; t2 += 2) {
          float2 sv = ld2<BF16>(ln1s, l * 64 + kb + t2);
          float2 bv = ld2<BF16>(ln1b, l * 64 + kb + t2);
          vv[t2]     = (sH[m * 66 + kb + t2] - mu) * rr * sv.x + bv.x;
          vv[t2 + 1] = (sH[m * 66 + kb + t2 + 1] - mu) * rr * sv.y + bv.y;
        }
        pk.x = pack_bf2(vv[0], vv[1]); pk.y = pack_bf2(vv[2], vv[3]);
        pk.z = pack_bf2(vv[4], vv[5]); pk.w = pack_bf2(vv[6], vv[7]);
      }
      ((i32x4*)(sm + O_XNF))[s] = pk;
    }
    __syncthreads();

    // ---- QKVG MFMA: 72 jobs / 8 waves ----
    {
      const bf16x8* xnf = (const bf16x8*)(sm + O_XNF);
      for (int j = w; j < 72; j += 8) {
        int mt = j / 24, nt = j % 24;
        const bf16x8* wf; int ntl, dst;
        if (nt < 4)       { wf = FRB + LB;        ntl = nt;      dst = 0; }
        else if (nt < 8)  { wf = FRB + LB + 512;  ntl = nt - 4;  dst = 1; }
        else if (nt < 16) { wf = FRB + LB + 1024; ntl = nt - 8;  dst = 2; }
        else              { wf = FRB + LB + 2048; ntl = nt - 16; dst = 3; }
        f32x4 acc = {0.f, 0.f, 0.f, 0.f};
#pragma unroll
        for (int kt = 0; kt < 2; ++kt)
          acc = MFMA(xnf[(mt * 2 + kt) * 64 + lane], wf[(ntl * 2 + kt) * 64 + lane], acc, 0, 0, 0);
        int n = ntl * 16 + ln;
        if (dst == 0) {
#pragma unroll
          for (int i = 0; i < 4; ++i) {
            int m = mt * 16 + lq * 4 + i;
            if (m < 34) sQ[m * 68 + n] = acc[i];
          }
        } else if (dst == 1) {
#pragma unroll
          for (int i = 0; i < 4; ++i) {
            int m = mt * 16 + lq * 4 + i;
            if (m < 34) {
              int img = (m >= 17), t = m - img * 17;
              sKT[img * 1152 + n * 18 + t] = acc[i];
            }
          }
        } else if (dst == 2) {
          // V transposed: sVbT[img][c][t], u16 pitch 20
#pragma unroll
          for (int i = 0; i < 4; ++i) {
            int m = mt * 16 + lq * 4 + i;
            if (m < 34) {
              __hip_bfloat16 hv = __float2bfloat16(acc[i]);
              unsigned short us;
              __builtin_memcpy(&us, &hv, 2);
              int img = (m >= 17), t = m - img * 17;
              sVbT[img * 2560 + n * 20 + t] = us;
            }
          }
        } else {
#pragma unroll
          for (int i = 0; i < 4; ++i) {
            int m = mt * 16 + lq * 4 + i;
            if (m < 34) {
              __hip_bfloat16 hv = __float2bfloat16(acc[i]);
              unsigned short us;
              __builtin_memcpy(&us, &hv, 2);
              sGb[m * 136 + n] = us;
            }
          }
        }
      }
    }
    __syncthreads();

    // ---- rotary: Q (linear) + KT (transposed, *0.25) ----
    for (int idx = tid; idx < 2176; idx += 512) {
      if (idx < 1088) {
        int m = idx >> 5, pr = idx & 31, d0 = 2 * pr;
        int t = m % 17;
        float sv = sSin[t * 16 + (d0 & 15)], cv = sCos[t * 16 + (d0 & 15)];
        float x0 = sQ[m * 68 + d0], x1 = sQ[m * 68 + d0 + 1];
        sQ[m * 68 + d0]     = x0 * cv - x1 * sv;
        sQ[m * 68 + d0 + 1] = x1 * cv + x0 * sv;
      } else {
        int r = idx - 1088;
        int img = r / 544, r2 = r % 544, pr = r2 / 17, t = r2 % 17, d0 = 2 * pr;
        float sv = sSin[t * 16 + (d0 & 15)], cv = sCos[t * 16 + (d0 & 15)];
        int a0 = img * 1152 + d0 * 18 + t, a1 = a0 + 18;
        float x0 = sKT[a0], x1 = sKT[a1];
        sKT[a0] = (x0 * cv - x1 * sv) * 0.25f;
        sKT[a1] = (x1 * cv + x0 * sv) * 0.25f;
      }
    }
    __syncthreads();

    // ---- scores, u-pairs: 1224 jobs, each writes (u0,u0+1) ----
    for (int idx = tid; idx < 1224; idx += 512) {
      int up = idx % 9, rest = idx / 9;
      int t = rest % 17, rest2 = rest / 17;
      int hh = rest2 & 3, img = rest2 >> 2;
      int u0 = 2 * up, u1 = u0 + 1;
      int dmb = hh * 289 + t * 17;
      int scb = img * 1360 + hh * 340 + t * 20;
      float out0 = 0.f, out1 = 0.f;
      if (u0 <= t) {
        const float* kp = sKT + img * 1152 + hh * 288 + u0;
        const float4* q4 = (const float4*)(sQ + (img * 17 + t) * 68 + hh * 16);
        float4 qa = q4[0], qb = q4[1], qc = q4[2], qd = q4[3];
        float a0, a1;
        float2 kv;
        kv = *(const float2*)(kp + 0);   a0  = qa.x * kv.x; a1  = qa.x * kv.y;
        kv = *(const float2*)(kp + 18);  a0 += qa.y * kv.x; a1 += qa.y * kv.y;
        kv = *(const float2*)(kp + 36);  a0 += qa.z * kv.x; a1 += qa.z * kv.y;
        kv = *(const float2*)(kp + 54);  a0 += qa.w * kv.x; a1 += qa.w * kv.y;
        kv = *(const float2*)(kp + 72);  a0 += qb.x * kv.x; a1 += qb.x * kv.y;
        kv = *(const float2*)(kp + 90);  a0 += qb.y * kv.x; a1 += qb.y * kv.y;
        kv = *(const float2*)(kp + 108); a0 += qb.z * kv.x; a1 += qb.z * kv.y;
        kv = *(const float2*)(kp + 126); a0 += qb.w * kv.x; a1 += qb.w * kv.y;
        kv = *(const float2*)(kp + 144); a0 += qc.x * kv.x; a1 += qc.x * kv.y;
        kv = *(const float2*)(kp + 162); a0 += qc.y * kv.x; a1 += qc.y * kv.y;
        kv = *(const float2*)(kp + 180); a0 += qc.z * kv.x; a1 += qc.z * kv.y;
        kv = *(const float2*)(kp + 198); a0 += qc.w * kv.x; a1 += qc.w * kv.y;
        kv = *(const float2*)(kp + 216); a0 += qd.x * kv.x; a1 += qd.x * kv.y;
        kv = *(const float2*)(kp + 234); a0 += qd.y * kv.x; a1 += qd.y * kv.y;
        kv = *(const float2*)(kp + 252); a0 += qd.z * kv.x; a1 += qd.z * kv.y;
        kv = *(const float2*)(kp + 270); a0 += qd.w * kv.x; a1 += qd.w * kv.y;
        out0 = a0 * sDM[dmb + u0];
        if (u1 <= t) out1 = a1 * sDM[dmb + u1];
      }
      sSC[scb + u0] = out0;
      if (u1 < 17) sSC[scb + u1] = out1;
    }
    __syncthreads();

    // ---- denominators ----
    if (tid < 136) {
      const float* base = sSC + tid * 20;
      float s = 0.f;
      for (int u = 0; u < 17; ++u) s += base[u];
      float den = fabsf(s);
      if (den < 1.f) den = 1.f;
      sST[68 + tid] = 1.f / den;
    }
    __syncthreads();

    // ---- AV via MFMA 32x32x16: 8 jobs (img, head), one per wave ----
    {
      int img = w >> 2, hh = w & 3;
      int cl = lane & 31, kh = lane >> 5;   // cl: A-row t / B-col c; kh: k-half
      int tt = (cl < 17) ? cl : 16;         // clamp invalid rows (discarded at store)
      const float* scb = sSC + img * 1360 + hh * 340;
      float den = sST[68 + img * 68 + hh * 17 + tt];
      // A0: P[t][u], u = kh*8 + j (j=0..7), denom folded in
      const float4* a4 = (const float4*)(scb + tt * 20 + kh * 8);
      float4 av0 = a4[0], av1 = a4[1];
      i32x4 ap;
      ap.x = pack_bf2(av0.x * den, av0.y * den);
      ap.y = pack_bf2(av0.z * den, av0.w * den);
      ap.z = pack_bf2(av1.x * den, av1.y * den);
      ap.w = pack_bf2(av1.z * den, av1.w * den);
      // B0: V[u][c], u = kh*8 + j, c = cl (local), from transposed V
      const unsigned short* vcol = sVbT + img * 2560 + (hh * 32 + cl) * 20 + kh * 8;
      const uint2* vq = (const uint2*)vcol;
      uint2 v0 = vq[0], v1 = vq[1];
      i32x4 bp; bp.x = (int)v0.x; bp.y = (int)v0.y; bp.z = (int)v1.x; bp.w = (int)v1.y;
      f32x16 acc = {0.f, 0.f, 0.f, 0.f, 0.f, 0.f, 0.f, 0.f,
                    0.f, 0.f, 0.f, 0.f, 0.f, 0.f, 0.f, 0.f};
      acc = MFMA32(as_bf(ap), as_bf(bp), acc, 0, 0, 0);
      // u = 16 tail: only lane-half kh==0, slot j==0 is nonzero
      i32x4 a1 = {0, 0, 0, 0}, b1 = {0, 0, 0, 0};
      if (kh == 0) {
        float s16 = scb[tt * 20 + 16] * den;
        __hip_bfloat16 hb = __float2bfloat16(s16);
        unsigned short us;
        __builtin_memcpy(&us, &hb, 2);
        a1.x = (int)(unsigned)us;
        b1.x = (int)(unsigned)sVbT[img * 2560 + (hh * 32 + cl) * 20 + 16];
      }
      acc = MFMA32(as_bf(a1), as_bf(b1), acc, 0, 0, 0);
      // store: C layout col=lane&31, row=(reg&3)+8*(reg>>2)+4*(lane>>5)
      int cg = hh * 32 + cl;
#pragma unroll
      for (int r = 0; r < 16; ++r) {
        int t = (r & 3) + 8 * (r >> 2) + 4 * kh;
        if (t < 17) sO[(img * 17 + t) * 130 + cg] = acc[r];
      }
    }
    __syncthreads();

    // ---- group norm stats: 2 lanes per row ----
    if (tid < 272) {
      int row = tid >> 1, sub = tid & 1;  // row = img*68 + hh*17 + t
      int img = row / 68, hr = row % 68, hh = hr / 17, t = hr % 17;
      int m = img * 17 + t;
      const float* op = sO + m * 130 + hh * 32 + sub * 16;
      float s1 = 0.f, s2 = 0.f;
#pragma unroll
      for (int i = 0; i < 16; ++i) { float v = op[i]; s1 += v; s2 += v * v; }
      s1 += __shfl_xor(s1, 1); s2 += __shfl_xor(s2, 1);
      if (sub == 0) {
        float mu = s1 * (1.f / 32.f);
        float var = s2 * (1.f / 32.f) - mu * mu;
        sST[204 + row] = mu;
        sST[340 + row] = rsqrtf(var + 1e-5f);
      }
    }
    __syncthreads();

    // ---- groupnorm + silu gate -> OA frags ----
    for (int s = tid; s < 768; s += 512) {
      int mt = s >> 8, kt = (s >> 6) & 3, la = s & 63;
      int q = la >> 4, m = mt * 16 + (la & 15);
      int cb = kt * 32 + q * 8;
      i32x4 pk = {0, 0, 0, 0};
      if (m < 34) {
        int img = (m >= 17), t = m - img * 17;
        int sti = img * 68 + kt * 17 + t;
        float mu = sST[204 + sti], rr = sST[340 + sti];
        float vv[8];
#pragma unroll
        for (int q2 = 0; q2 < 8; ++q2) {
          int c = cb + q2;
          float on = (sO[m * 130 + c] - mu) * rr;
          float gv = bfu(sGb[m * 136 + c]);
          vv[q2] = on * (gv / (1.f + __expf(-gv)));
        }
        pk.x = pack_bf2(vv[0], vv[1]); pk.y = pack_bf2(vv[2], vv[3]);
        pk.z = pack_bf2(vv[4], vv[5]); pk.w = pack_bf2(vv[6], vv[7]);
      }
      ((i32x4*)(sm + O_SCA))[s] = pk;
    }
    __syncthreads();

    // ---- Wo MFMA: 12 jobs / 8 waves; += residual ----
    {
      const bf16x8* oaf = (const bf16x8*)(sm + O_SCA);
      const bf16x8* wof = FRB + LB + 3072;
      for (int j = w; j < 12; j += 8) {
        int mt = j / 4, nt = j % 4;
        f32x4 acc = {0.f, 0.f, 0.f, 0.f};
#pragma unroll
        for (int kt = 0; kt < 4; ++kt)
          acc = MFMA(oaf[(mt * 4 + kt) * 64 + lane], wof[(nt * 4 + kt) * 64 + lane], acc, 0, 0, 0);
        int n = nt * 16 + ln;
#pragma unroll
        for (int i = 0; i < 4; ++i) {
          int m = mt * 16 + lq * 4 + i;
          if (m < 34) sH[m * 66 + n] += acc[i];
        }
      }
    }
    __syncthreads();

    // ---- ln2 stats ----
    if (tid < 272) {
      int m = tid >> 3, sub = tid & 7;
      const float* hp = sH + m * 66 + sub * 8;
      float s1 = 0.f, s2 = 0.f;
#pragma unroll
      for (int i = 0; i < 8; ++i) { float v = hp[i]; s1 += v; s2 += v * v; }
      s1 += __shfl_xor(s1, 1); s2 += __shfl_xor(s2, 1);
      s1 += __shfl_xor(s1, 2); s2 += __shfl_xor(s2, 2);
      s1 += __shfl_xor(s1, 4); s2 += __shfl_xor(s2, 4);
      if (sub == 0) {
        float mu = s1 * (1.f / 64.f);
        float var = s2 * (1.f / 64.f) - mu * mu;
        sST[m] = mu;
        sST[34 + m] = rsqrtf(var + 1e-5f);
      }
    }
    __syncthreads();

    // ---- ln2 -> XNp plain bf16 (34 x pitch 72) ----
    for (int idx = tid; idx < 1088; idx += 512) {
      int m = idx >> 5, dp = idx & 31, d0 = 2 * dp;
      float mu = sST[m], rr = sST[34 + m];
      float2 sv = ld2<BF16>(ln2s, l * 64 + d0);
      float2 bv = ld2<BF16>(ln2b, l * 64 + d0);
      float a0 = (sH[m * 66 + d0] - mu) * rr * sv.x + bv.x;
      float a1 = (sH[m * 66 + d0 + 1] - mu) * rr * sv.y + bv.y;
      ((unsigned*)(sm + O_XNF))[m * 36 + dp] = pack_bf2(a0, a1);
    }
    __syncthreads();

    // ---- FFN1 (64->12) + gelu ----
    for (int item = tid; item < 408; item += 512) {
      int m = item / 12, e = item % 12;
      float acc = ld<BF16>(b1, l * 12 + e);
      const float4* xp4 = (const float4*)(sm + O_XNF);
      const i32x4* w1t = (const i32x4*)(FR + 12288 + l * 33536 + 32768 + e * 64);
#pragma unroll
      for (int d4 = 0; d4 < 8; ++d4) {
        float4 xv = xp4[m * 9 + d4];
        i32x4 wv = w1t[d4];
        float2 xa = unpk(__float_as_uint(xv.x)), wa = unpk((unsigned)wv.x);
        float2 xb = unpk(__float_as_uint(xv.y)), wb = unpk((unsigned)wv.y);
        float2 xc = unpk(__float_as_uint(xv.z)), wc = unpk((unsigned)wv.z);
        float2 xd = unpk(__float_as_uint(xv.w)), wd = unpk((unsigned)wv.w);
        acc += xa.x * wa.x + xa.y * wa.y + xb.x * wb.x + xb.y * wb.y
             + xc.x * wc.x + xc.y * wc.y + xd.x * wd.x + xd.y * wd.y;
      }
      float inner = 0.7978845608028654f * (acc + 0.044715f * acc * acc * acc);
      sFF[item] = 0.5f * acc * (1.f + tanhf(inner));
    }
    __syncthreads();

    // ---- FFN2 (12->64) + residual ----
    for (int idx = tid; idx < 1088; idx += 512) {
      int m = idx >> 5, dp = idx & 31, d0 = 2 * dp;
      float2 bv = ld2<BF16>(b2, l * 64 + d0);
      float a0 = bv.x, a1 = bv.y;
      const float* ff = sFF + m * 12;
#pragma unroll
      for (int e = 0; e < 12; ++e) {
        float2 wv = ld2<BF16>(w2, (l * 12 + e) * 64 + d0);
        a0 += ff[e] * wv.x;
        a1 += ff[e] * wv.y;
      }
      sH[m * 66 + d0] += a0;
      sH[m * 66 + d0 + 1] += a1;
    }
    __syncthreads();
  }

  // ---- final: lnf (last token each image), neck, head ----
  if (tid < 2) {
    int m = tid * 17 + 16;
    float s1 = 0.f, s2 = 0.f;
    for (int d = 0; d < 64; ++d) {
      float v = sH[m * 66 + d];
      s1 += v; s2 += v * v;
    }
    float mu = s1 * (1.f / 64.f);
    float var = s2 * (1.f / 64.f) - mu * mu;
    sST[tid] = mu;
    sST[2 + tid] = rsqrtf(var + 1e-5f);
  }
  __syncthreads();
  if (tid < 32) {
    int img = tid >> 4, jn = tid & 15;
    int m = img * 17 + 16;
    float mu = sST[img], rr = sST[2 + img];
    float acc = ld<BF16>(neckb, jn);
    for (int d = 0; d < 64; ++d) {
      float yn = (sH[m * 66 + d] - mu) * rr * ld<BF16>(lnfs, d) + ld<BF16>(lnfb, d);
      acc += yn * ld<BF16>(neckw, d * 16 + jn);
    }
    sST[8 + img * 16 + jn] = acc;
  }
  __syncthreads();
  if (tid < 20) {
    int img = tid / 10, o = tid % 10;
    float acc = ld<BF16>(headb, o);
#pragma unroll
    for (int e = 0; e < 16; ++e) acc += sST[8 + img * 16 + e] * ld<BF16>(headw, e * 10 + o);
    if (BF16) {
      ((__hip_bfloat16*)out)[(img0 + img) * 10 + o] = __float2bfloat16(acc);
    } else {
      ((float*)out)[(img0 + img) * 10 + o] = acc;
    }
  }
}

extern "C" void kernel_launch(void* const* d_in, const int* in_sizes, int n_in,
                              void* d_out, int out_size, void* d_ws, size_t ws_size,
                              hipStream_t stream) {
  float* tab = (float*)d_ws;
  unsigned short* frag = (unsigned short*)((char*)d_ws + 8192);

  setup_tables<<<dim3(1), dim3(256), 0, stream>>>(tab, d_in[0]);

  const int prepBlocks = (FRAG_TOT + 255) / 256;
  prep_frags<false><<<dim3(prepBlocks), dim3(256), 0, stream>>>(
      d_in[1], d_in[5], d_in[6], d_in[7], d_in[8], d_in[9], d_in[12], tab, frag);
  prep_frags<true><<<dim3(prepBlocks), dim3(256), 0, stream>>>(
      d_in[1], d_in[5], d_in[6], d_in[7], d_in[8], d_in[9], d_in[12], tab, frag);

  const int B = in_sizes[0] / 3072;
  const int grid = B / 2;

  vit_fused<false><<<dim3(grid), dim3(512), 0, stream>>>(
      d_in[0], d_in[2], d_in[3], d_in[4], d_in[10], d_in[11], d_in[13],
      d_in[14], d_in[15], d_in[16], d_in[17], d_in[18], d_in[19], d_in[20],
      d_in[21], d_in[22], d_in[23], tab, frag, d_out);
  vit_fused<true><<<dim3(grid), dim3(512), 0, stream>>>(
      d_in[0], d_in[2], d_in[3], d_in[4], d_in[10], d_in[11], d_in[13],
      d_in[14], d_in[15], d_in[16], d_in[17], d_in[18], d_in[19], d_in[20],
      d_in[21], d_in[22], d_in[23], tab, frag, d_out);
}

// Round 2
// 1004.232 us; speedup vs baseline: 1.4255x; 1.2699x over previous
//
#include <hip/hip_runtime.h>
#include <hip/hip_bf16.h>

#define NLAY 8
#define MFMA __builtin_amdgcn_mfma_f32_16x16x32_bf16
#define MFMA32 __builtin_amdgcn_mfma_f32_32x32x16_bf16

typedef __attribute__((ext_vector_type(8))) short bf16x8;
typedef __attribute__((ext_vector_type(4))) float f32x4;
typedef __attribute__((ext_vector_type(16))) float f32x16;
typedef __attribute__((ext_vector_type(4))) int i32x4;

template <bool BF16>
__device__ __forceinline__ float ld(const void* p, int i) {
  if (BF16) {
    unsigned short u = ((const unsigned short*)p)[i];
    return __uint_as_float(((unsigned)u) << 16);
  }
  return ((const float*)p)[i];
}

template <bool BF16>
__device__ __forceinline__ float2 ld2(const void* p, int i) {  // i even
  float2 r;
  if (BF16) {
    unsigned u = ((const unsigned*)p)[i >> 1];
    r.x = __uint_as_float(u << 16);
    r.y = __uint_as_float(u & 0xffff0000u);
  } else {
    r = ((const float2*)p)[i >> 1];
  }
  return r;
}

__device__ __forceinline__ float bfu(unsigned short u) {
  return __uint_as_float(((unsigned)u) << 16);
}

__device__ __forceinline__ unsigned pack_bf2(float a, float b) {
  __hip_bfloat16 ha = __float2bfloat16(a), hb = __float2bfloat16(b);
  unsigned short ua, ub;
  __builtin_memcpy(&ua, &ha, 2);
  __builtin_memcpy(&ub, &hb, 2);
  return ((unsigned)ub << 16) | (unsigned)ua;
}

__device__ __forceinline__ float2 unpk(unsigned u) {
  float2 r;
  r.x = __uint_as_float(u << 16);
  r.y = __uint_as_float(u & 0xffff0000u);
  return r;
}

__device__ __forceinline__ bf16x8 as_bf(i32x4 v) {
  bf16x8 r;
  __builtin_memcpy(&r, &v, 16);
  return r;
}

// ws[0..271]=sin, ws[272..543]=cos, ws[544..1699]=dmask, ws[1700]=dtype flag
__global__ void setup_tables(float* __restrict__ ws, const void* __restrict__ x) {
  int tid = threadIdx.x;
  for (int idx = tid; idx < 272; idx += 256) {
    int t = idx >> 4, j = idx & 15;
    float a = powf(10000.f, -(float)(j >> 1) / 7.f);
    float arg = (float)t * a;
    ws[idx] = sinf(arg);
    ws[272 + idx] = cosf(arg);
  }
  for (int row = tid; row < 68; row += 256) {
    int hh = row / 17, t = row % 17;
    float gamma = 1.f - exp2f(-5.f - 4.f * (float)hh / 3.f);
    float sum = 0.f;
    for (int u = 0; u <= t; ++u) sum += powf(gamma, (float)(t - u));
    float rn = rsqrtf(sum);
    for (int u = 0; u < 17; ++u)
      ws[544 + row * 17 + u] = (u <= t) ? powf(gamma, (float)(t - u)) * rn : 0.f;
  }
  if (tid == 0) {
    const unsigned short* u16 = (const unsigned short*)x;
    int sane = 0;
    for (int i = 0; i < 128; ++i) {
      float v = __uint_as_float(((unsigned)u16[2 * i]) << 16);
      float av = fabsf(v);
      if (v == 0.f || (av > 1e-8f && av < 1e4f)) sane++;
    }
    ws[1700] = (sane >= 64) ? 1.f : 0.f;
  }
}

// Pre-swizzle weights into MFMA B-fragment order (bf16), into ws+8192 bytes.
// Old regions [0, 280576) unchanged; new: per-layer w1 B-frags (1024) + w2 B-frags (2048).
#define FRAG_OLD 280576
#define FRAG_TOT 305152
template <bool BF16>
__global__ void prep_frags(const void* __restrict__ patch_w,
                           const void* __restrict__ Wq, const void* __restrict__ Wk,
                           const void* __restrict__ Wv, const void* __restrict__ Wg,
                           const void* __restrict__ Wo, const void* __restrict__ w1,
                           const void* __restrict__ w2,
                           const float* __restrict__ tab,
                           unsigned short* __restrict__ frag) {
  if ((tab[1700] > 0.5f) != BF16) return;
  int g = blockIdx.x * 256 + threadIdx.x;
  if (g >= FRAG_TOT) return;
  float v;
  if (g < 12288) {  // patch_w: K=192 (kt6), N=64 (nt4)
    int nt = g / 3072, r = g % 3072, kt = r / 512, r2 = r % 512, la = r2 >> 3, j = r2 & 7;
    int n = nt * 16 + (la & 15), k = kt * 32 + (la >> 4) * 8 + j;
    v = ld<BF16>(patch_w, k * 64 + n);
  } else if (g < FRAG_OLD) {
    int gg = g - 12288, l = gg / 33536, o = gg % 33536;
    if (o < 8192) {  // Wq / Wk
      const void* W = (o < 4096) ? Wq : Wk;
      int e = o & 4095;
      int nt = e / 1024, r = e % 1024, kt = r / 512, r2 = r % 512, la = r2 >> 3, j = r2 & 7;
      int n = nt * 16 + (la & 15), k = kt * 32 + (la >> 4) * 8 + j;
      v = ld<BF16>(W, l * 4096 + k * 64 + n);
    } else if (o < 24576) {  // Wv / Wg
      const void* W = (o < 16384) ? Wv : Wg;
      int e = (o - 8192) & 8191;
      int nt = e / 1024, r = e % 1024, kt = r / 512, r2 = r % 512, la = r2 >> 3, j = r2 & 7;
      int n = nt * 16 + (la & 15), k = kt * 32 + (la >> 4) * 8 + j;
      v = ld<BF16>(W, l * 8192 + k * 128 + n);
    } else if (o < 32768) {  // Wo
      int e = o - 24576;
      int nt = e / 2048, r = e % 2048, kt = r / 512, r2 = r % 512, la = r2 >> 3, j = r2 & 7;
      int n = nt * 16 + (la & 15), k = kt * 32 + (la >> 4) * 8 + j;
      v = ld<BF16>(Wo, l * 8192 + k * 64 + n);
    } else {  // legacy w1T (unused)
      int e = o - 32768, eo = e / 64, d = e % 64;
      v = ld<BF16>(w1, l * 768 + d * 12 + eo);
    }
  } else {  // new: w1 / w2 B-frags
    int gg = g - FRAG_OLD, l = gg / 3072, o = gg % 3072;
    if (o < 1024) {  // w1 B-frag: n=e (pad>=12), k=d, kt 0..1
      int kt = o >> 9, r = o & 511, la = r >> 3, j = r & 7;
      int n = la & 15, k = kt * 32 + (la >> 4) * 8 + j;
      v = (n < 12) ? ld<BF16>(w1, l * 768 + k * 12 + n) : 0.f;
    } else {  // w2 B-frag: n=d (nt 0..3), k=e (pad>=12), K=32
      int e2 = o - 1024;
      int nt = e2 >> 9, r = e2 & 511, la = r >> 3, j = r & 7;
      int n = nt * 16 + (la & 15), k = (la >> 4) * 8 + j;
      v = (k < 12) ? ld<BF16>(w2, (l * 12 + k) * 64 + n) : 0.f;
    }
  }
  __hip_bfloat16 h = __float2bfloat16(v);
  unsigned short us;
  __builtin_memcpy(&us, &h, 2);
  frag[g] = us;
}

// LDS float offsets
#define O_DM   0      // 1156 (dmask * 0.25 folded)
#define O_SIN  1156   // 272
#define O_COS  1428   // 272
#define O_ST   1700   // 512
#define O_H    2212   // 2244: H fp32 34x66
#define O_XNF  4456   // 1536: XN A-frags (ln1 / ln2)
#define O_FF   5992   // 408
#define O_R    6400   // 4624: Q 34x68 + K 34x68 / alias O fp32 34x130
#define O_SCA  11024  // 3072: patch A-frags / SC fp32 2x4x17x20 (2720) / OA frags
#define O_VG   14096  // 4872: VT bf16 2x128x20 (2560 f) + G bf16 34x136 (2312 f)
#define SM_TOT 18968

template <bool BF16>
__global__ void __launch_bounds__(512)
vit_fused(const void* __restrict__ x, const void* __restrict__ patch_b,
          const void* __restrict__ cls, const void* __restrict__ pos,
          const void* __restrict__ ln1s, const void* __restrict__ ln1b,
          const void* __restrict__ b1, const void* __restrict__ b2,
          const void* __restrict__ ln2s, const void* __restrict__ ln2b,
          const void* __restrict__ lnfs, const void* __restrict__ lnfb,
          const void* __restrict__ neckw, const void* __restrict__ neckb,
          const void* __restrict__ headw, const void* __restrict__ headb,
          const float* __restrict__ tab, const unsigned short* __restrict__ FR,
          void* __restrict__ out) {
  if ((tab[1700] > 0.5f) != BF16) return;

  const int tid = threadIdx.x;
  const int lane = tid & 63, w = tid >> 6;  // w in 0..7
  const int lq = lane >> 4, ln = lane & 15;
  const int img0 = 2 * blockIdx.x;

  __shared__ __align__(16) float sm[SM_TOT];
  float* sDM  = sm + O_DM;
  float* sSin = sm + O_SIN;
  float* sCos = sm + O_COS;
  float* sST  = sm + O_ST;
  float* sH   = sm + O_H;
  float* sFF  = sm + O_FF;
  float* sQ   = sm + O_R;          // 34x68
  float* sK   = sm + O_R + 2312;   // 34x68
  float* sO   = sm + O_R;          // alias, 34x130
  float* sSC  = sm + O_SCA;        // 2 x 4 x 17 x 20 (pitch-20 rows)
  unsigned short* sVbT = (unsigned short*)(sm + O_VG);          // 2 x 128 x 20 (c-major, u inner)
  unsigned short* sGb  = (unsigned short*)(sm + O_VG) + 5120;   // 34x136
  const bf16x8* FRB = (const bf16x8*)FR;

  // ---- stage tables + patch A-frags + cls rows ----
  for (int i = tid; i < 1156; i += 512) sDM[i] = tab[544 + i] * 0.25f;  // K-scale folded
  for (int i = tid; i < 272; i += 512) { sSin[i] = tab[i]; sCos[i] = tab[272 + i]; }
  for (int s = tid; s < 768; s += 512) {  // patch A-frags into O_SCA
    int mt = s / 384, r = s % 384, kt = r / 64, la = r % 64;
    int p = la & 15, q = la >> 4;
    int kb = kt * 32 + q * 8;
    int c = kb >> 6, rem = kb & 63, a = rem >> 3;
    int pi = p >> 2, pj = p & 3;
    int src = (img0 + mt) * 3072 + c * 1024 + (pi * 8 + a) * 32 + pj * 8;
    float v[8];
#pragma unroll
    for (int t2 = 0; t2 < 8; t2 += 2) {
      float2 pv = ld2<BF16>(x, src + t2);
      v[t2] = pv.x; v[t2 + 1] = pv.y;
    }
    i32x4 pk;
    pk.x = pack_bf2(v[0], v[1]); pk.y = pack_bf2(v[2], v[3]);
    pk.z = pack_bf2(v[4], v[5]); pk.w = pack_bf2(v[6], v[7]);
    ((i32x4*)(sm + O_SCA))[s] = pk;
  }
  if (tid < 128) {  // cls token rows
    int img = tid >> 6, n = tid & 63;
    sH[(img * 17) * 66 + n] = ld<BF16>(cls, n) + ld<BF16>(pos, n);
  }
  __syncthreads();

  // ---- patch embed MFMA: 8 jobs = 2mt x 4nt, one per wave ----
  {
    int mt = w >> 2, nt = w & 3;
    f32x4 acc = {0.f, 0.f, 0.f, 0.f};
    const bf16x8* paf = (const bf16x8*)(sm + O_SCA);
#pragma unroll
    for (int kt = 0; kt < 6; ++kt)
      acc = MFMA(paf[(mt * 6 + kt) * 64 + lane], FRB[(nt * 6 + kt) * 64 + lane], acc, 0, 0, 0);
    int n = nt * 16 + ln;
    float pb = ld<BF16>(patch_b, n);
#pragma unroll
    for (int i = 0; i < 4; ++i) {
      int t = 1 + lq * 4 + i;
      sH[(mt * 17 + t) * 66 + n] = acc[i] + pb + ld<BF16>(pos, t * 64 + n);
    }
  }
  __syncthreads();

  for (int l = 0; l < NLAY; ++l) {
    const int LB = 1536 + l * 4192;  // layer base, bf16x8 slots

    // ---- ln1 stats: 8 lanes per row + shuffle reduce ----
    if (tid < 272) {
      int m = tid >> 3, sub = tid & 7;
      const float* hp = sH + m * 66 + sub * 8;
      float s1 = 0.f, s2 = 0.f;
#pragma unroll
      for (int i = 0; i < 8; ++i) { float v = hp[i]; s1 += v; s2 += v * v; }
      s1 += __shfl_xor(s1, 1); s2 += __shfl_xor(s2, 1);
      s1 += __shfl_xor(s1, 2); s2 += __shfl_xor(s2, 2);
      s1 += __shfl_xor(s1, 4); s2 += __shfl_xor(s2, 4);
      if (sub == 0) {
        float mu = s1 * (1.f / 64.f);
        float var = s2 * (1.f / 64.f) - mu * mu;
        sST[m] = mu;
        sST[34 + m] = rsqrtf(var + 1e-5f);
      }
    }
    __syncthreads();

    // ---- ln1 -> XN A-frags (bf16) ----
    for (int s = tid; s < 384; s += 512) {
      int mt = s >> 7, kt = (s >> 6) & 1, la = s & 63;
      int m = mt * 16 + (la & 15), q = la >> 4;
      int kb = kt * 32 + q * 8;
      i32x4 pk = {0, 0, 0, 0};
      if (m < 34) {
        float mu = sST[m], rr = sST[34 + m];
        float vv[8];
#pragma unroll
        for (int t2 = 0; t2 < 8; t2 += 2) {
          float2 sv = ld2<BF16>(ln1s, l * 64 + kb + t2);
          float2 bv = ld2<BF16>(ln1b, l * 64 + kb + t2);
          vv[t2]     = (sH[m * 66 + kb + t2] - mu) * rr * sv.x + bv.x;
          vv[t2 + 1] = (sH[m * 66 + kb + t2 + 1] - mu) * rr * sv.y + bv.y;
        }
        pk.x = pack_bf2(vv[0], vv[1]); pk.y = pack_bf2(vv[2], vv[3]);
        pk.z = pack_bf2(vv[4], vv[5]); pk.w = pack_bf2(vv[6], vv[7]);
      }
      ((i32x4*)(sm + O_XNF))[s] = pk;
    }
    __syncthreads();

    // ---- QKVG MFMA: 72 jobs / 8 waves ----
    {
      const bf16x8* xnf = (const bf16x8*)(sm + O_XNF);
      for (int j = w; j < 72; j += 8) {
        int mt = j / 24, nt = j % 24;
        const bf16x8* wf; int ntl, dst;
        if (nt < 4)       { wf = FRB + LB;        ntl = nt;      dst = 0; }
        else if (nt < 8)  { wf = FRB + LB + 512;  ntl = nt - 4;  dst = 1; }
        else if (nt < 16) { wf = FRB + LB + 1024; ntl = nt - 8;  dst = 2; }
        else              { wf = FRB + LB + 2048; ntl = nt - 16; dst = 3; }
        f32x4 acc = {0.f, 0.f, 0.f, 0.f};
#pragma unroll
        for (int kt = 0; kt < 2; ++kt)
          acc = MFMA(xnf[(mt * 2 + kt) * 64 + lane], wf[(ntl * 2 + kt) * 64 + lane], acc, 0, 0, 0);
        int n = ntl * 16 + ln;
        if (dst == 0) {
#pragma unroll
          for (int i = 0; i < 4; ++i) {
            int m = mt * 16 + lq * 4 + i;
            if (m < 34) sQ[m * 68 + n] = acc[i];
          }
        } else if (dst == 1) {
#pragma unroll
          for (int i = 0; i < 4; ++i) {
            int m = mt * 16 + lq * 4 + i;
            if (m < 34) sK[m * 68 + n] = acc[i];
          }
        } else if (dst == 2) {
          // V transposed: sVbT[img][c][t], u16 pitch 20
#pragma unroll
          for (int i = 0; i < 4; ++i) {
            int m = mt * 16 + lq * 4 + i;
            if (m < 34) {
              __hip_bfloat16 hv = __float2bfloat16(acc[i]);
              unsigned short us;
              __builtin_memcpy(&us, &hv, 2);
              int img = (m >= 17), t = m - img * 17;
              sVbT[img * 2560 + n * 20 + t] = us;
            }
          }
        } else {
#pragma unroll
          for (int i = 0; i < 4; ++i) {
            int m = mt * 16 + lq * 4 + i;
            if (m < 34) {
              __hip_bfloat16 hv = __float2bfloat16(acc[i]);
              unsigned short us;
              __builtin_memcpy(&us, &hv, 2);
              sGb[m * 136 + n] = us;
            }
          }
        }
      }
    }
    __syncthreads();

    // ---- scores via MFMA 32x32x16: 8 jobs (img, head), rotary fused in frag build ----
    {
      int img = w >> 2, hh = w & 3;
      int cl = lane & 31, kh = lane >> 5;
      int tt = (cl < 17) ? cl : 16;  // clamp garbage rows (discarded at store)
      int rb = (img * 17 + tt) * 68 + hh * 16 + kh * 8;
      int sb = tt * 16 + kh * 8;
      float4 s0 = *(const float4*)(sSin + sb), s1 = *(const float4*)(sSin + sb + 4);
      float4 c0 = *(const float4*)(sCos + sb), c1 = *(const float4*)(sCos + sb + 4);
      float4 qa = *(const float4*)(sQ + rb), qb = *(const float4*)(sQ + rb + 4);
      i32x4 ap;
      ap.x = pack_bf2(qa.x * c0.x - qa.y * s0.x, qa.y * c0.y + qa.x * s0.y);
      ap.y = pack_bf2(qa.z * c0.z - qa.w * s0.z, qa.w * c0.w + qa.z * s0.w);
      ap.z = pack_bf2(qb.x * c1.x - qb.y * s1.x, qb.y * c1.y + qb.x * s1.y);
      ap.w = pack_bf2(qb.z * c1.z - qb.w * s1.z, qb.w * c1.w + qb.z * s1.w);
      float4 ka = *(const float4*)(sK + rb), kb = *(const float4*)(sK + rb + 4);
      i32x4 bp;
      bp.x = pack_bf2(ka.x * c0.x - ka.y * s0.x, ka.y * c0.y + ka.x * s0.y);
      bp.y = pack_bf2(ka.z * c0.z - ka.w * s0.z, ka.w * c0.w + ka.z * s0.w);
      bp.z = pack_bf2(kb.x * c1.x - kb.y * s1.x, kb.y * c1.y + kb.x * s1.y);
      bp.w = pack_bf2(kb.z * c1.z - kb.w * s1.z, kb.w * c1.w + kb.z * s1.w);
      f32x16 acc = {0.f, 0.f, 0.f, 0.f, 0.f, 0.f, 0.f, 0.f,
                    0.f, 0.f, 0.f, 0.f, 0.f, 0.f, 0.f, 0.f};
      acc = MFMA32(as_bf(ap), as_bf(bp), acc, 0, 0, 0);
      if (cl < 17) {  // valid u column; dmask (incl 0.25) zeroes u>t
        int scb = img * 1360 + hh * 340;
        const float* dmb = sDM + hh * 289;
#pragma unroll
        for (int r = 0; r < 16; ++r) {
          int t = (r & 3) + 8 * (r >> 2) + 4 * kh;
          if (t < 17) sSC[scb + t * 20 + cl] = acc[r] * dmb[t * 17 + cl];
        }
      }
    }
    __syncthreads();

    // ---- denominators ----
    if (tid < 136) {
      const float* base = sSC + tid * 20;
      float s = 0.f;
      for (int u = 0; u < 17; ++u) s += base[u];
      float den = fabsf(s);
      if (den < 1.f) den = 1.f;
      sST[68 + tid] = 1.f / den;
    }
    __syncthreads();

    // ---- AV via MFMA 32x32x16: 8 jobs (img, head), one per wave ----
    {
      int img = w >> 2, hh = w & 3;
      int cl = lane & 31, kh = lane >> 5;   // cl: A-row t / B-col c; kh: k-half
      int tt = (cl < 17) ? cl : 16;         // clamp invalid rows (discarded at store)
      const float* scb = sSC + img * 1360 + hh * 340;
      float den = sST[68 + img * 68 + hh * 17 + tt];
      const float4* a4 = (const float4*)(scb + tt * 20 + kh * 8);
      float4 av0 = a4[0], av1 = a4[1];
      i32x4 ap;
      ap.x = pack_bf2(av0.x * den, av0.y * den);
      ap.y = pack_bf2(av0.z * den, av0.w * den);
      ap.z = pack_bf2(av1.x * den, av1.y * den);
      ap.w = pack_bf2(av1.z * den, av1.w * den);
      const unsigned short* vcol = sVbT + img * 2560 + (hh * 32 + cl) * 20 + kh * 8;
      const uint2* vq = (const uint2*)vcol;
      uint2 v0 = vq[0], v1 = vq[1];
      i32x4 bp; bp.x = (int)v0.x; bp.y = (int)v0.y; bp.z = (int)v1.x; bp.w = (int)v1.y;
      f32x16 acc = {0.f, 0.f, 0.f, 0.f, 0.f, 0.f, 0.f, 0.f,
                    0.f, 0.f, 0.f, 0.f, 0.f, 0.f, 0.f, 0.f};
      acc = MFMA32(as_bf(ap), as_bf(bp), acc, 0, 0, 0);
      i32x4 a1 = {0, 0, 0, 0}, b1v = {0, 0, 0, 0};
      if (kh == 0) {  // u = 16 tail
        float s16 = scb[tt * 20 + 16] * den;
        __hip_bfloat16 hb = __float2bfloat16(s16);
        unsigned short us;
        __builtin_memcpy(&us, &hb, 2);
        a1.x = (int)(unsigned)us;
        b1v.x = (int)(unsigned)sVbT[img * 2560 + (hh * 32 + cl) * 20 + 16];
      }
      acc = MFMA32(as_bf(a1), as_bf(b1v), acc, 0, 0, 0);
      int cg = hh * 32 + cl;
#pragma unroll
      for (int r = 0; r < 16; ++r) {
        int t = (r & 3) + 8 * (r >> 2) + 4 * kh;
        if (t < 17) sO[(img * 17 + t) * 130 + cg] = acc[r];
      }
    }
    __syncthreads();

    // ---- group norm stats: 2 lanes per row ----
    if (tid < 272) {
      int row = tid >> 1, sub = tid & 1;  // row = img*68 + hh*17 + t
      int img = row / 68, hr = row % 68, hh = hr / 17, t = hr % 17;
      int m = img * 17 + t;
      const float* op = sO + m * 130 + hh * 32 + sub * 16;
      float s1 = 0.f, s2 = 0.f;
#pragma unroll
      for (int i = 0; i < 16; ++i) { float v = op[i]; s1 += v; s2 += v * v; }
      s1 += __shfl_xor(s1, 1); s2 += __shfl_xor(s2, 1);
      if (sub == 0) {
        float mu = s1 * (1.f / 32.f);
        float var = s2 * (1.f / 32.f) - mu * mu;
        sST[204 + row] = mu;
        sST[340 + row] = rsqrtf(var + 1e-5f);
      }
    }
    __syncthreads();

    // ---- groupnorm + silu gate -> OA frags ----
    for (int s = tid; s < 768; s += 512) {
      int mt = s >> 8, kt = (s >> 6) & 3, la = s & 63;
      int q = la >> 4, m = mt * 16 + (la & 15);
      int cb = kt * 32 + q * 8;
      i32x4 pk = {0, 0, 0, 0};
      if (m < 34) {
        int img = (m >= 17), t = m - img * 17;
        int sti = img * 68 + kt * 17 + t;
        float mu = sST[204 + sti], rr = sST[340 + sti];
        float vv[8];
#pragma unroll
        for (int q2 = 0; q2 < 8; ++q2) {
          int c = cb + q2;
          float on = (sO[m * 130 + c] - mu) * rr;
          float gv = bfu(sGb[m * 136 + c]);
          vv[q2] = on * (gv / (1.f + __expf(-gv)));
        }
        pk.x = pack_bf2(vv[0], vv[1]); pk.y = pack_bf2(vv[2], vv[3]);
        pk.z = pack_bf2(vv[4], vv[5]); pk.w = pack_bf2(vv[6], vv[7]);
      }
      ((i32x4*)(sm + O_SCA))[s] = pk;
    }
    __syncthreads();

    // ---- Wo MFMA: 12 jobs / 8 waves; += residual ----
    {
      const bf16x8* oaf = (const bf16x8*)(sm + O_SCA);
      const bf16x8* wof = FRB + LB + 3072;
      for (int j = w; j < 12; j += 8) {
        int mt = j / 4, nt = j % 4;
        f32x4 acc = {0.f, 0.f, 0.f, 0.f};
#pragma unroll
        for (int kt = 0; kt < 4; ++kt)
          acc = MFMA(oaf[(mt * 4 + kt) * 64 + lane], wof[(nt * 4 + kt) * 64 + lane], acc, 0, 0, 0);
        int n = nt * 16 + ln;
#pragma unroll
        for (int i = 0; i < 4; ++i) {
          int m = mt * 16 + lq * 4 + i;
          if (m < 34) sH[m * 66 + n] += acc[i];
        }
      }
    }
    __syncthreads();

    // ---- ln2 stats ----
    if (tid < 272) {
      int m = tid >> 3, sub = tid & 7;
      const float* hp = sH + m * 66 + sub * 8;
      float s1 = 0.f, s2 = 0.f;
#pragma unroll
      for (int i = 0; i < 8; ++i) { float v = hp[i]; s1 += v; s2 += v * v; }
      s1 += __shfl_xor(s1, 1); s2 += __shfl_xor(s2, 1);
      s1 += __shfl_xor(s1, 2); s2 += __shfl_xor(s2, 2);
      s1 += __shfl_xor(s1, 4); s2 += __shfl_xor(s2, 4);
      if (sub == 0) {
        float mu = s1 * (1.f / 64.f);
        float var = s2 * (1.f / 64.f) - mu * mu;
        sST[m] = mu;
        sST[34 + m] = rsqrtf(var + 1e-5f);
      }
    }
    __syncthreads();

    // ---- ln2 -> XN2 A-frags (bf16) ----
    for (int s = tid; s < 384; s += 512) {
      int mt = s >> 7, kt = (s >> 6) & 1, la = s & 63;
      int m = mt * 16 + (la & 15), q = la >> 4;
      int kb = kt * 32 + q * 8;
      i32x4 pk = {0, 0, 0, 0};
      if (m < 34) {
        float mu = sST[m], rr = sST[34 + m];
        float vv[8];
#pragma unroll
        for (int t2 = 0; t2 < 8; t2 += 2) {
          float2 sv = ld2<BF16>(ln2s, l * 64 + kb + t2);
          float2 bv = ld2<BF16>(ln2b, l * 64 + kb + t2);
          vv[t2]     = (sH[m * 66 + kb + t2] - mu) * rr * sv.x + bv.x;
          vv[t2 + 1] = (sH[m * 66 + kb + t2 + 1] - mu) * rr * sv.y + bv.y;
        }
        pk.x = pack_bf2(vv[0], vv[1]); pk.y = pack_bf2(vv[2], vv[3]);
        pk.z = pack_bf2(vv[4], vv[5]); pk.w = pack_bf2(vv[6], vv[7]);
      }
      ((i32x4*)(sm + O_XNF))[s] = pk;
    }
    __syncthreads();

    // ---- FFN1 via MFMA: 3 jobs (mt), N=12 in one 16-tile, K=64; gelu at store ----
    if (w < 3) {
      const bf16x8* xnf = (const bf16x8*)(sm + O_XNF);
      const bf16x8* w1f = FRB + 35072 + l * 384;
      int mt = w;
      f32x4 acc = {0.f, 0.f, 0.f, 0.f};
#pragma unroll
      for (int kt = 0; kt < 2; ++kt)
        acc = MFMA(xnf[(mt * 2 + kt) * 64 + lane], w1f[kt * 64 + lane], acc, 0, 0, 0);
      if (ln < 12) {
        float b = ld<BF16>(b1, l * 12 + ln);
#pragma unroll
        for (int i = 0; i < 4; ++i) {
          int m = mt * 16 + lq * 4 + i;
          if (m < 34) {
            float a = acc[i] + b;
            float inner = 0.7978845608028654f * (a + 0.044715f * a * a * a);
            sFF[m * 12 + ln] = 0.5f * a * (1.f + tanhf(inner));
          }
        }
      }
    }
    __syncthreads();

    // ---- FFN2 via MFMA: 12 jobs (mt3 x nt4), K=32 (e padded); bias+residual at store ----
    {
      const bf16x8* w2f = FRB + 35072 + l * 384 + 128;
      for (int j = w; j < 12; j += 8) {
        int mt = j >> 2, nt = j & 3;
        i32x4 ap = {0, 0, 0, 0};
        int ma = mt * 16 + ln;
        if (ma < 34) {
          const float* fp = sFF + ma * 12;
          if (lq == 0) {
            ap.x = pack_bf2(fp[0], fp[1]); ap.y = pack_bf2(fp[2], fp[3]);
            ap.z = pack_bf2(fp[4], fp[5]); ap.w = pack_bf2(fp[6], fp[7]);
          } else if (lq == 1) {
            ap.x = pack_bf2(fp[8], fp[9]); ap.y = pack_bf2(fp[10], fp[11]);
          }
        }
        f32x4 acc = {0.f, 0.f, 0.f, 0.f};
        acc = MFMA(as_bf(ap), w2f[nt * 64 + lane], acc, 0, 0, 0);
        int n = nt * 16 + ln;
        float b = ld<BF16>(b2, l * 64 + n);
#pragma unroll
        for (int i = 0; i < 4; ++i) {
          int m = mt * 16 + lq * 4 + i;
          if (m < 34) sH[m * 66 + n] += acc[i] + b;
        }
      }
    }
    __syncthreads();
  }

  // ---- final: lnf (last token each image), neck, head ----
  if (tid < 2) {
    int m = tid * 17 + 16;
    float s1 = 0.f, s2 = 0.f;
    for (int d = 0; d < 64; ++d) {
      float v = sH[m * 66 + d];
      s1 += v; s2 += v * v;
    }
    float mu = s1 * (1.f / 64.f);
    float var = s2 * (1.f / 64.f) - mu * mu;
    sST[tid] = mu;
    sST[2 + tid] = rsqrtf(var + 1e-5f);
  }
  __syncthreads();
  if (tid < 32) {
    int img = tid >> 4, jn = tid & 15;
    int m = img * 17 + 16;
    float mu = sST[img], rr = sST[2 + img];
    float acc = ld<BF16>(neckb, jn);
    for (int d = 0; d < 64; ++d) {
      float yn = (sH[m * 66 + d] - mu) * rr * ld<BF16>(lnfs, d) + ld<BF16>(lnfb, d);
      acc += yn * ld<BF16>(neckw, d * 16 + jn);
    }
    sST[8 + img * 16 + jn] = acc;
  }
  __syncthreads();
  if (tid < 20) {
    int img = tid / 10, o = tid % 10;
    float acc = ld<BF16>(headb, o);
#pragma unroll
    for (int e = 0; e < 16; ++e) acc += sST[8 + img * 16 + e] * ld<BF16>(headw, e * 10 + o);
    if (BF16) {
      ((__hip_bfloat16*)out)[(img0 + img) * 10 + o] = __float2bfloat16(acc);
    } else {
      ((float*)out)[(img0 + img) * 10 + o] = acc;
    }
  }
}

extern "C" void kernel_launch(void* const* d_in, const int* in_sizes, int n_in,
                              void* d_out, int out_size, void* d_ws, size_t ws_size,
                              hipStream_t stream) {
  float* tab = (float*)d_ws;
  unsigned short* frag = (unsigned short*)((char*)d_ws + 8192);

  setup_tables<<<dim3(1), dim3(256), 0, stream>>>(tab, d_in[0]);

  const int prepBlocks = (FRAG_TOT + 255) / 256;
  prep_frags<false><<<dim3(prepBlocks), dim3(256), 0, stream>>>(
      d_in[1], d_in[5], d_in[6], d_in[7], d_in[8], d_in[9], d_in[12], d_in[14], tab, frag);
  prep_frags<true><<<dim3(prepBlocks), dim3(256), 0, stream>>>(
      d_in[1], d_in[5], d_in[6], d_in[7], d_in[8], d_in[9], d_in[12], d_in[14], tab, frag);

  const int B = in_sizes[0] / 3072;
  const int grid = B / 2;

  vit_fused<false><<<dim3(grid), dim3(512), 0, stream>>>(
      d_in[0], d_in[2], d_in[3], d_in[4], d_in[10], d_in[11], d_in[13],
      d_in[15], d_in[16], d_in[17], d_in[18], d_in[19], d_in[20], d_in[21],
      d_in[22], d_in[23], tab, frag, d_out);
  vit_fused<true><<<dim3(grid), dim3(512), 0, stream>>>(
      d_in[0], d_in[2], d_in[3], d_in[4], d_in[10], d_in[11], d_in[13],
      d_in[15], d_in[16], d_in[17], d_in[18], d_in[19], d_in[20], d_in[21],
      d_in[22], d_in[23], tab, frag, d_out);
}